// Round 1
// baseline (539.867 us; speedup 1.0000x reference)
//
#include <hip/hip_runtime.h>
#include <math.h>

#define EPS 1e-8f

// ---- sortable 64-bit key: descending value, tie -> lowest index ----
__device__ __forceinline__ unsigned long long make_key(float v, unsigned idx) {
    unsigned u = __float_as_uint(v);
    u = (u & 0x80000000u) ? ~u : (u | 0x80000000u);   // monotonic map
    return ((unsigned long long)u << 32) | (unsigned long long)(0xFFFFFFFFu - idx);
}
__device__ __forceinline__ float key_val(unsigned long long k) {
    unsigned u = (unsigned)(k >> 32);
    u = (u & 0x80000000u) ? (u & 0x7FFFFFFFu) : ~u;
    return __uint_as_float(u);
}
__device__ __forceinline__ unsigned key_idx(unsigned long long k) {
    return 0xFFFFFFFFu - (unsigned)(k & 0xFFFFFFFFu);
}

// ---- exact top-64 selection from M keys in LDS (keys are unique, >0) ----
// Eliminated entries are set to 0. Result keys written in descending order.
template <int M, int T>
__device__ void select_top64(unsigned long long* key, unsigned long long* out_keys) {
    __shared__ unsigned long long wk[T / 64];
    const int tid = threadIdx.x;
    const int w = tid >> 6;

    for (int s = 0; s < 64; ++s) {
        unsigned long long myb = 0ull;
        int bpos = -1;
#pragma unroll
        for (int j = tid; j < M; j += T) {
            unsigned long long kj = key[j];
            if (kj > myb) { myb = kj; bpos = j; }
        }
        // wave-level max
        unsigned long long rb = myb;
#pragma unroll
        for (int off = 32; off >= 1; off >>= 1) {
            unsigned long long o = __shfl_xor(rb, off, 64);
            if (o > rb) rb = o;
        }
        if ((tid & 63) == 0) wk[w] = rb;
        __syncthreads();
        unsigned long long gb = wk[0];
#pragma unroll
        for (int i = 1; i < T / 64; ++i)
            if (wk[i] > gb) gb = wk[i];
        // unique owner (keys unique, partitions disjoint) eliminates winner
        if (bpos >= 0 && myb == gb) key[bpos] = 0ull;
        if (tid == 0) out_keys[s] = gb;
        __syncthreads();
    }
}

// ---- pass A: score 1024 rows per block, emit block-local top-64 keys ----
__global__ __launch_bounds__(256) void score_topk_kernel(
    const float* __restrict__ q, const float4* __restrict__ emb,
    const float* __restrict__ rep, unsigned long long* __restrict__ out_keys) {
    __shared__ unsigned long long keys[1024];
    const int tid = threadIdx.x;
    const int lane = tid & 63;
    const int w = tid >> 6;
    const int base = blockIdx.x << 10;

    // per-lane query fragment (lane covers columns 4*lane..4*lane+3)
    float4 q4 = ((const float4*)q)[lane];
    float qsq = q4.x * q4.x + q4.y * q4.y + q4.z * q4.z + q4.w * q4.w;
#pragma unroll
    for (int off = 32; off >= 1; off >>= 1) qsq += __shfl_xor(qsq, off, 64);
    const float qn = fmaxf(sqrtf(qsq), EPS);

    for (int it = 0; it < 256; ++it) {
        const int rl = (it << 2) + w;      // row within block, one row per wave
        const int row = base + rl;
        float4 v = emb[(size_t)row * 64 + (size_t)lane];
        float d  = v.x * q4.x + v.y * q4.y + v.z * q4.z + v.w * q4.w;
        float sq = v.x * v.x + v.y * v.y + v.z * v.z + v.w * v.w;
#pragma unroll
        for (int off = 32; off >= 1; off >>= 1) {
            d  += __shfl_xor(d, off, 64);
            sq += __shfl_xor(sq, off, 64);
        }
        if (lane == 0) {
            float en = fmaxf(sqrtf(sq), EPS);
            float sim = d / (en * qn);
            float boost = 1.0f + 0.1f * tanhf(0.5f * rep[row]);
            keys[rl] = make_key(sim * boost, (unsigned)row);
        }
    }
    __syncthreads();
    select_top64<1024, 256>(keys, out_keys + ((size_t)blockIdx.x << 6));
}

// ---- merge: each block reduces M candidate keys -> 64 ----
template <int M>
__global__ __launch_bounds__(256) void merge_kernel(
    const unsigned long long* __restrict__ in_keys,
    unsigned long long* __restrict__ out_keys) {
    __shared__ unsigned long long keys[M];
    const int tid = threadIdx.x;
    const size_t base = (size_t)blockIdx.x * M;
    for (int j = tid; j < M; j += 256) keys[j] = in_keys[base + j];
    __syncthreads();
    select_top64<M, 256>(keys, out_keys + ((size_t)blockIdx.x << 6));
}

// ---- final: 4096 candidates -> top-64, decode and write output ----
__global__ __launch_bounds__(256) void final_kernel(
    const unsigned long long* __restrict__ in_keys, float* __restrict__ out) {
    __shared__ unsigned long long keys[4096];
    __shared__ unsigned long long topk[64];
    const int tid = threadIdx.x;
    for (int j = tid; j < 4096; j += 256) keys[j] = in_keys[j];
    __syncthreads();
    select_top64<4096, 256>(keys, topk);
    __syncthreads();
    if (tid < 64) {
        unsigned long long k = topk[tid];
        out[tid] = key_val(k);
        out[64 + tid] = (float)key_idx(k);   // idx < 2^20, exact in fp32
    }
}

extern "C" void kernel_launch(void* const* d_in, const int* in_sizes, int n_in,
                              void* d_out, int out_size, void* d_ws, size_t ws_size,
                              hipStream_t stream) {
    const float* q   = (const float*)d_in[0];   // [256]
    const float* emb = (const float*)d_in[1];   // [N,256]
    const float* rep = (const float*)d_in[2];   // [N]
    const int N = in_sizes[2];                  // 1048576
    const int nblocks = N >> 10;                // 1024 blocks of 1024 rows

    unsigned long long* k1 = (unsigned long long*)d_ws;      // nblocks*64 keys (512 KB)
    unsigned long long* k2 = k1 + (size_t)nblocks * 64;      // 64*64 keys (32 KB)

    score_topk_kernel<<<nblocks, 256, 0, stream>>>(q, (const float4*)emb, rep, k1);
    merge_kernel<1024><<<(nblocks * 64) / 1024, 256, 0, stream>>>(k1, k2);
    final_kernel<<<1, 256, 0, stream>>>(k2, (float*)d_out);
}

// Round 2
// 257.067 us; speedup vs baseline: 2.1001x; 2.1001x over previous
//
#include <hip/hip_runtime.h>
#include <math.h>

#define EPS 1e-8f
#define NBINS 4096
#define BIN_SHIFT 20    // 32 - log2(NBINS)
#define CAP 4096        // candidate buffer capacity (expected ~100-300 used)

// monotonic map: float -> u32 preserving order (no NaNs in this problem)
__device__ __forceinline__ unsigned mono(float v) {
    unsigned u = __float_as_uint(v);
    return (u & 0x80000000u) ? ~u : (u | 0x80000000u);
}
__device__ __forceinline__ float unmono(unsigned u) {
    return __uint_as_float((u & 0x80000000u) ? (u & 0x7FFFFFFFu) : ~u);
}

// ---- A: score all rows, write monotonic keys, build global histogram ----
// 16 lanes per row: lane covers float4 columns (l&15)+16j, j=0..3.
// Each wave scores 4 rows per iteration.
__global__ __launch_bounds__(256) void score_hist_kernel(
    const float4* __restrict__ q4, const float4* __restrict__ emb,
    const float* __restrict__ rep, unsigned* __restrict__ keys_out,
    unsigned* __restrict__ ghist, int rows_per_block) {
    __shared__ unsigned hist[NBINS];
    const int tid = threadIdx.x;
    for (int j = tid; j < NBINS; j += 256) hist[j] = 0;

    const int lane = tid & 63;
    const int w = tid >> 6;
    const int c = lane & 15;    // column group within row
    const int sub = lane >> 4;  // which of the wave's 4 rows

    float4 ql[4];
    float qsq = 0.f;
#pragma unroll
    for (int j = 0; j < 4; ++j) {
        ql[j] = q4[c + 16 * j];
        qsq += ql[j].x * ql[j].x + ql[j].y * ql[j].y + ql[j].z * ql[j].z + ql[j].w * ql[j].w;
    }
#pragma unroll
    for (int off = 8; off >= 1; off >>= 1) qsq += __shfl_xor(qsq, off, 64);
    const float qn = fmaxf(sqrtf(qsq), EPS);

    __syncthreads();  // hist zeroed

    const int base = blockIdx.x * rows_per_block;
    const int iters = rows_per_block >> 4;  // 16 rows per block-iteration
    for (int it = 0; it < iters; ++it) {
        const int row = base + (it << 4) + (w << 2) + sub;
        const float4* rp = emb + (size_t)row * 64 + c;
        float d = 0.f, sq = 0.f;
#pragma unroll
        for (int j = 0; j < 4; ++j) {
            float4 v = rp[16 * j];
            d  += v.x * ql[j].x + v.y * ql[j].y + v.z * ql[j].z + v.w * ql[j].w;
            sq += v.x * v.x + v.y * v.y + v.z * v.z + v.w * v.w;
        }
#pragma unroll
        for (int off = 8; off >= 1; off >>= 1) {
            d  += __shfl_xor(d, off, 64);
            sq += __shfl_xor(sq, off, 64);
        }
        if (c == 0) {
            const float en = fmaxf(sqrtf(sq), EPS);
            const float sim = d / (en * qn);
            const float boost = 1.0f + 0.1f * tanhf(0.5f * rep[row]);
            const unsigned u = mono(sim * boost);
            keys_out[row] = u;
            atomicAdd(&hist[u >> BIN_SHIFT], 1u);
        }
    }
    __syncthreads();
    for (int j = tid; j < NBINS; j += 256) {
        const unsigned h = hist[j];
        if (h) atomicAdd(&ghist[j], h);
    }
}

// ---- B: find largest bin b with suffix-count(b) >= k; threshold = b << BIN_SHIFT ----
__global__ __launch_bounds__(256) void scan_kernel(
    const unsigned* __restrict__ ghist, unsigned* __restrict__ thresh, int k) {
    __shared__ unsigned partial[256];
    __shared__ unsigned suffix[256];  // count in bins strictly above this chunk
    const int tid = threadIdx.x;
    unsigned p = 0;
#pragma unroll
    for (int j = 0; j < NBINS / 256; ++j) p += ghist[tid * (NBINS / 256) + j];
    partial[tid] = p;
    __syncthreads();
    if (tid == 0) {
        unsigned run = 0;
        for (int t = 255; t >= 0; --t) { suffix[t] = run; run += partial[t]; }
    }
    __syncthreads();
    const unsigned above = suffix[tid];
    if (above < (unsigned)k && above + partial[tid] >= (unsigned)k) {
        // unique crossing chunk: scan its bins from the top
        unsigned run = above;
        int b = tid * (NBINS / 256);
        for (int j = NBINS / 256 - 1; j >= 0; --j) {
            run += ghist[tid * (NBINS / 256) + j];
            if (run >= (unsigned)k) { b = tid * (NBINS / 256) + j; break; }
        }
        thresh[0] = ((unsigned)b) << BIN_SHIFT;
    }
}

// ---- C: compact candidates >= threshold (order-invariant downstream) ----
__global__ __launch_bounds__(256) void compact_kernel(
    const unsigned* __restrict__ keys, const unsigned* __restrict__ thresh,
    unsigned* __restrict__ counter, unsigned long long* __restrict__ cand, int n) {
    const unsigned T = thresh[0];
    const int i0 = (blockIdx.x * 256 + threadIdx.x) * 4;
    if (i0 >= n) return;
    const uint4 kv = *(const uint4*)(keys + i0);
#pragma unroll
    for (int j = 0; j < 4; ++j) {
        const unsigned kj = j == 0 ? kv.x : j == 1 ? kv.y : j == 2 ? kv.z : kv.w;
        if (kj >= T) {
            const unsigned p = atomicAdd(counter, 1u);
            if (p < CAP)
                cand[p] = ((unsigned long long)kj << 32) |
                          (unsigned long long)(0xFFFFFFFFu - (unsigned)(i0 + j));
        }
    }
}

// ---- D: exact top-k over the candidates ----
__global__ __launch_bounds__(256) void final_select_kernel(
    const unsigned long long* __restrict__ cand, const unsigned* __restrict__ counter,
    float* __restrict__ out, int k) {
    __shared__ unsigned long long keys[CAP];
    __shared__ unsigned long long wk[4];
    const int tid = threadIdx.x;
    const int w = tid >> 6;
    const int count = min((int)counter[0], CAP);
    for (int j = tid; j < count; j += 256) keys[j] = cand[j];
    __syncthreads();
    for (int s = 0; s < k; ++s) {
        unsigned long long myb = 0ull;
        int bpos = -1;
        for (int j = tid; j < count; j += 256) {
            const unsigned long long kj = keys[j];
            if (kj > myb) { myb = kj; bpos = j; }
        }
        unsigned long long rb = myb;
#pragma unroll
        for (int off = 32; off >= 1; off >>= 1) {
            const unsigned long long o = __shfl_xor(rb, off, 64);
            if (o > rb) rb = o;
        }
        if ((tid & 63) == 0) wk[w] = rb;
        __syncthreads();
        unsigned long long gb = wk[0];
#pragma unroll
        for (int i = 1; i < 4; ++i) if (wk[i] > gb) gb = wk[i];
        if (bpos >= 0 && myb == gb) keys[bpos] = 0ull;  // unique owner removes winner
        if (tid == 0) {
            out[s]     = unmono((unsigned)(gb >> 32));
            out[k + s] = (float)(0xFFFFFFFFu - (unsigned)(gb & 0xFFFFFFFFu));
        }
        __syncthreads();
    }
}

extern "C" void kernel_launch(void* const* d_in, const int* in_sizes, int n_in,
                              void* d_out, int out_size, void* d_ws, size_t ws_size,
                              hipStream_t stream) {
    const float* q   = (const float*)d_in[0];   // [256]
    const float* emb = (const float*)d_in[1];   // [N,256]
    const float* rep = (const float*)d_in[2];   // [N]
    const int N = in_sizes[2];                  // 1048576
    const int k = out_size / 2;                 // 64

    // ws layout: keys u32[N] | ghist u32[NBINS] | thresh u32 | counter u32 | cand u64[CAP]
    unsigned* keys    = (unsigned*)d_ws;
    unsigned* ghist   = keys + N;
    unsigned* thresh  = ghist + NBINS;
    unsigned* counter = thresh + 1;
    unsigned long long* cand = (unsigned long long*)(counter + 1);  // byte offset 8-aligned

    // zero histogram + threshold + counter each call (ws is not re-poisoned)
    hipMemsetAsync(ghist, 0, (NBINS + 2) * sizeof(unsigned), stream);

    const int nblocksA = 2048;                  // 8 blocks/CU, full 32 waves/CU
    score_hist_kernel<<<nblocksA, 256, 0, stream>>>(
        (const float4*)q, (const float4*)emb, rep, keys, ghist, N / nblocksA);
    scan_kernel<<<1, 256, 0, stream>>>(ghist, thresh, k);
    compact_kernel<<<N / 1024, 256, 0, stream>>>(keys, thresh, counter, cand, N);
    final_select_kernel<<<1, 256, 0, stream>>>(cand, counter, (float*)d_out, k);
}